// Round 14
// baseline (311.097 us; speedup 1.0000x reference)
//
#include <hip/hip_runtime.h>

#define B    128
#define D_IN 256
#define H    256

#define BH      (B * H)            // 32768
#define BIG     (B * D_IN * H)     // 8388608
#define OFF_H1   0
#define OFF_H2   (1 * BH)
#define OFF_NGM0 (2 * BH)
#define OFF_NGM1 (3 * BH)
#define OFF_NGM2 (4 * BH)
#define OFF_NGM3 (5 * BH)
#define OFF_NGM4 (6 * BH)
#define OFF_NGM5 (OFF_NGM4 + 1 * BIG)
#define OFF_NGM6 (OFF_NGM4 + 2 * BIG)
#define OFF_NGM7 (OFF_NGM4 + 3 * BIG)

// ---------------------------------------------------------------------------
// Kernel 1: per-(b,h) small work. v2: 4-way k-split GEMV.
//   Phase A: thread t = (ks, hq), ks = t>>6 (k-slice), hq = t&63 (h-quad).
//     Partial dot over k in [ks*64, ks*64+64) for 4 h values via float4 loads
//     (64 iters, 2 coalesced float4 loads each — 4x the MLP of v1, 4x shorter
//      chain). Partials -> LDS.
//   Phase B: thread t owns h = t. Sum 4 slice partials from LDS (stride-256
//     float reads, conflict-free), then transcendentals, c1/c2, relu, d1/d2,
//     ngm0..3, and the 6 coefficient arrays into ws.
// grid = B blocks, 256 threads.
// ---------------------------------------------------------------------------
__global__ __launch_bounds__(256) void k_small(
    const float* __restrict__ x,   const float* __restrict__ hc1, const float* __restrict__ hc2,
    const float* __restrict__ gm0, const float* __restrict__ gm1,
    const float* __restrict__ gm2, const float* __restrict__ gm3,
    const float* __restrict__ rp,  const float* __restrict__ thp,
    const float* __restrict__ wx1, const float* __restrict__ wx2,
    float* __restrict__ out, float* __restrict__ ws)
{
    const int b = blockIdx.x;
    const int t = threadIdx.x;

    __shared__ float  xs[D_IN];
    __shared__ float4 s1q[4 * 64];   // [slice][h-quad] partials for w1x
    __shared__ float4 s2q[4 * 64];   // [slice][h-quad] partials for w2x

    xs[t] = x[b * D_IN + t];
    __syncthreads();

    // ---- Phase A: partial GEMV ----
    const int hq = t & 63;           // h-quad: h = hq*4 + c
    const int ks = t >> 6;           // k-slice 0..3

    const float4* __restrict__ wx1q = (const float4*)wx1;  // [k][64] quads
    const float4* __restrict__ wx2q = (const float4*)wx2;

    float4 a1 = make_float4(0.f, 0.f, 0.f, 0.f);
    float4 a2 = make_float4(0.f, 0.f, 0.f, 0.f);
    const int k0 = ks * 64;
#pragma unroll 8
    for (int kk = 0; kk < 64; ++kk) {
        const int k = k0 + kk;
        const float xv = xs[k];
        const float4 w1 = wx1q[k * 64 + hq];
        const float4 w2 = wx2q[k * 64 + hq];
        a1.x = fmaf(xv, w1.x, a1.x); a1.y = fmaf(xv, w1.y, a1.y);
        a1.z = fmaf(xv, w1.z, a1.z); a1.w = fmaf(xv, w1.w, a1.w);
        a2.x = fmaf(xv, w2.x, a2.x); a2.y = fmaf(xv, w2.y, a2.y);
        a2.z = fmaf(xv, w2.z, a2.z); a2.w = fmaf(xv, w2.w, a2.w);
    }
    s1q[ks * 64 + hq] = a1;
    s2q[ks * 64 + hq] = a2;
    __syncthreads();

    // ---- Phase B: per-h epilogue (thread t owns h = t) ----
    const int h = t;
    const float* s1f = (const float*)s1q;   // float idx: slice*256 + h
    const float* s2f = (const float*)s2q;
    const float acc1 = s1f[0 * 256 + h] + s1f[1 * 256 + h]
                     + s1f[2 * 256 + h] + s1f[3 * 256 + h];
    const float acc2 = s2f[0 * 256 + h] + s2f[1 * 256 + h]
                     + s2f[2 * 256 + h] + s2f[3 * 256 + h];

    const float er  = expf(rp[h]);
    const float r   = expf(-er);
    const float th  = expf(thp[h]);
    const float g   = r * cosf(th);
    const float phi = r * sinf(th);
    const float nrm = sqrtf(1.0f - r * r);

    const int idx = b * H + h;
    const float h1 = hc1[idx], h2 = hc2[idx];

    const float c1 = g * h1 - phi * h2 + nrm * acc1;
    const float c2 = g * h2 + phi * h1 + nrm * acc2;
    const float d1 = (c1 > 0.0f) ? 1.0f : 0.0f;
    const float d2 = (c2 > 0.0f) ? 1.0f : 0.0f;

    out[OFF_H1 + idx] = fmaxf(c1, 0.0f);
    out[OFF_H2 + idx] = fmaxf(c2, 0.0f);

    const float m0 = gm0[idx], m1 = gm1[idx], m2 = gm2[idx], m3 = gm3[idx];

    const float dgr = -er * g;           // d_g_w_r
    const float dpr = -er * phi;         // d_phi_w_r
    const float dgt = -th * phi;         // d_g_w_th
    const float dpt =  th * g;           // d_phi_w_th
    const float dnr =  er * r * r / nrm; // d_norm_w_r

    out[OFF_NGM0 + idx] = d1 * (dgr * h1 + g * m0 - dpr * h2 - phi * m1 + dnr * acc1);
    out[OFF_NGM1 + idx] = d2 * (dgr * h2 + g * m1 + dpr * h1 + phi * m0 + dnr * acc2);
    out[OFF_NGM2 + idx] = d1 * (dgt * h1 + g * m2 - dpt * h2 - phi * m3);
    out[OFF_NGM3 + idx] = d2 * (dgt * h2 + g * m3 + dpt * h1 + phi * m2);

    ws[0 * BH + idx] = d1 * g;
    ws[1 * BH + idx] = d1 * phi;
    ws[2 * BH + idx] = d1 * nrm;
    ws[3 * BH + idx] = d2 * g;
    ws[4 * BH + idx] = d2 * phi;
    ws[5 * BH + idx] = d2 * nrm;
}

// ---------------------------------------------------------------------------
// Kernel 2 v2: one thread per quad — max TLP / MLP.
//   Round-1's 4-j register blocking capped at 48 VGPR -> serialized iters,
//   ~3 KB in-flight/CU vs ~9 KB needed (measured 31% peak). This form: 11
//   independent loads per thread, no loop, 8192 blocks (32K waves) -> full
//   CU occupancy and ~10 outstanding refs/thread.
//   i: b = i>>14, j = (i>>6)&255, h4 = i&63. All gm/o accesses 16B coalesced;
//   x wave-uniform; coeffs L2/L3-resident (768 KB).
// ---------------------------------------------------------------------------
__global__ __launch_bounds__(256) void k_big(
    const float4* __restrict__ gm4, const float4* __restrict__ gm5,
    const float4* __restrict__ gm6, const float4* __restrict__ gm7,
    const float*  __restrict__ x,
    const float4* __restrict__ wsq,
    float4* __restrict__ o4, float4* __restrict__ o5,
    float4* __restrict__ o6, float4* __restrict__ o7)
{
    const int i  = blockIdx.x * 256 + threadIdx.x;   // quad index, 0..2097151
    const int b  = i >> 14;
    const int j  = (i >> 6) & (D_IN - 1);
    const int h4 = i & 63;

    const int CQ = BH / 4;                           // 8192 quads per coeff array
    const int ci = (b << 6) + h4;

    const float4 A1 = wsq[0 * CQ + ci];
    const float4 B1 = wsq[1 * CQ + ci];
    const float4 N1 = wsq[2 * CQ + ci];
    const float4 A2 = wsq[3 * CQ + ci];
    const float4 B2 = wsq[4 * CQ + ci];
    const float4 N2 = wsq[5 * CQ + ci];

    const float xv = x[(b << 8) + j];

    const float4 g4 = gm4[i], g5 = gm5[i], g6 = gm6[i], g7 = gm7[i];

    float4 r4, r5, r6, r7;
#define COMP(c)                                                       \
    r4.c = fmaf(N1.c, xv, fmaf(A1.c, g4.c, -(B1.c * g5.c)));          \
    r5.c = fmaf(A2.c, g5.c, B2.c * g4.c);                             \
    r6.c = fmaf(A1.c, g6.c, -(B1.c * g7.c));                          \
    r7.c = fmaf(N2.c, xv, fmaf(A2.c, g7.c, B2.c * g6.c));
    COMP(x) COMP(y) COMP(z) COMP(w)
#undef COMP

    o4[i] = r4;
    o5[i] = r5;
    o6[i] = r6;
    o7[i] = r7;
}

extern "C" void kernel_launch(void* const* d_in, const int* in_sizes, int n_in,
                              void* d_out, int out_size, void* d_ws, size_t ws_size,
                              hipStream_t stream) {
    const float* x_t  = (const float*)d_in[0];
    const float* hc1  = (const float*)d_in[1];
    const float* hc2  = (const float*)d_in[2];
    const float* gm0  = (const float*)d_in[3];
    const float* gm1  = (const float*)d_in[4];
    const float* gm2  = (const float*)d_in[5];
    const float* gm3  = (const float*)d_in[6];
    const float* gm4  = (const float*)d_in[7];
    const float* gm5  = (const float*)d_in[8];
    const float* gm6  = (const float*)d_in[9];
    const float* gm7  = (const float*)d_in[10];
    const float* rp   = (const float*)d_in[11];
    const float* thp  = (const float*)d_in[12];
    const float* wx1  = (const float*)d_in[13];
    const float* wx2  = (const float*)d_in[14];

    float* out = (float*)d_out;
    float* ws  = (float*)d_ws;

    k_small<<<B, 256, 0, stream>>>(x_t, hc1, hc2, gm0, gm1, gm2, gm3,
                                   rp, thp, wx1, wx2, out, ws);

    const int quads = BIG / 4;                 // 2,097,152
    k_big<<<quads / 256, 256, 0, stream>>>(
        (const float4*)gm4, (const float4*)gm5, (const float4*)gm6, (const float4*)gm7,
        x_t, (const float4*)ws,
        (float4*)(out + OFF_NGM4), (float4*)(out + OFF_NGM5),
        (float4*)(out + OFF_NGM6), (float4*)(out + OFF_NGM7));
}

// Round 16
// 271.621 us; speedup vs baseline: 1.1453x; 1.1453x over previous
//
#include <hip/hip_runtime.h>

#define B    128
#define D_IN 256
#define H    256

#define BH      (B * H)            // 32768
#define BIG     (B * D_IN * H)     // 8388608
#define OFF_H1   0
#define OFF_H2   (1 * BH)
#define OFF_NGM0 (2 * BH)
#define OFF_NGM1 (3 * BH)
#define OFF_NGM2 (4 * BH)
#define OFF_NGM3 (5 * BH)
#define OFF_NGM4 (6 * BH)
#define OFF_NGM5 (OFF_NGM4 + 1 * BIG)
#define OFF_NGM6 (OFF_NGM4 + 2 * BIG)
#define OFF_NGM7 (OFF_NGM4 + 3 * BIG)

// native clang vector type — __builtin_nontemporal_store rejects
// HIP_vector_type<float,4>, but accepts ext_vector_type(4) floats.
typedef float floatx4 __attribute__((ext_vector_type(4)));

// ---------------------------------------------------------------------------
// Kernel 1 v3: GEMV + epilogue, 4x the blocks of v2 (all CUs busy), 16-way
// k-split (16-iter fully-unrolled chains, 32 float4 loads in flight).
//   grid = B*4 = 512 blocks (b = bid>>2, hseg = bid&3 -> 64 h per block).
//   Phase A: thread t = (ks = t>>4, hq = t&15). Partial dot over 16 k for
//     4 h (one float4 column quad). wx is 512 KB total -> L2-resident.
//   Phase B: threads 0..63 reduce 16 partials from LDS (conflict-free),
//     then transcendentals, c1/c2, relu, d1/d2, ngm0..3, coeffs -> ws.
// ---------------------------------------------------------------------------
__global__ __launch_bounds__(256, 2) void k_small(
    const float* __restrict__ x,   const float* __restrict__ hc1, const float* __restrict__ hc2,
    const float* __restrict__ gm0, const float* __restrict__ gm1,
    const float* __restrict__ gm2, const float* __restrict__ gm3,
    const float* __restrict__ rp,  const float* __restrict__ thp,
    const float* __restrict__ wx1, const float* __restrict__ wx2,
    float* __restrict__ out, float* __restrict__ ws)
{
    const int bid  = blockIdx.x;
    const int b    = bid >> 2;
    const int hseg = bid & 3;        // h in [hseg*64, hseg*64+64)
    const int t    = threadIdx.x;

    __shared__ float  xs[D_IN];
    __shared__ float4 s1q[16 * 16];  // [ks][hq] partials for w1x
    __shared__ float4 s2q[16 * 16];

    xs[t] = x[b * D_IN + t];
    __syncthreads();

    // ---- Phase A ----
    const int hq = t & 15;           // local h-quad 0..15
    const int ks = t >> 4;           // k-slice 0..15
    const int gq = hseg * 16 + hq;   // global h-quad 0..63

    const float4* __restrict__ wx1q = (const float4*)wx1;  // [k][64] quads
    const float4* __restrict__ wx2q = (const float4*)wx2;

    float4 a1 = make_float4(0.f, 0.f, 0.f, 0.f);
    float4 a2 = make_float4(0.f, 0.f, 0.f, 0.f);
    const int k0 = ks * 16;
#pragma unroll
    for (int kk = 0; kk < 16; ++kk) {
        const int k = k0 + kk;
        const float xv = xs[k];
        const float4 w1 = wx1q[k * 64 + gq];
        const float4 w2 = wx2q[k * 64 + gq];
        a1.x = fmaf(xv, w1.x, a1.x); a1.y = fmaf(xv, w1.y, a1.y);
        a1.z = fmaf(xv, w1.z, a1.z); a1.w = fmaf(xv, w1.w, a1.w);
        a2.x = fmaf(xv, w2.x, a2.x); a2.y = fmaf(xv, w2.y, a2.y);
        a2.z = fmaf(xv, w2.z, a2.z); a2.w = fmaf(xv, w2.w, a2.w);
    }
    s1q[ks * 16 + hq] = a1;
    s2q[ks * 16 + hq] = a2;
    __syncthreads();

    // ---- Phase B: threads 0..63, one h each ----
    if (t < 64) {
        const int h   = hseg * 64 + t;
        // float view: [ks][hq][4] -> float index ks*64 + (local h = t)
        const float* s1f = (const float*)s1q;
        const float* s2f = (const float*)s2q;
        float acc1 = 0.f, acc2 = 0.f;
#pragma unroll
        for (int s = 0; s < 16; ++s) {
            acc1 += s1f[s * 64 + t];
            acc2 += s2f[s * 64 + t];
        }

        const float er  = expf(rp[h]);
        const float r   = expf(-er);
        const float th  = expf(thp[h]);
        const float g   = r * cosf(th);
        const float phi = r * sinf(th);
        const float nrm = sqrtf(1.0f - r * r);

        const int idx = b * H + h;
        const float h1 = hc1[idx], h2 = hc2[idx];

        const float c1 = g * h1 - phi * h2 + nrm * acc1;
        const float c2 = g * h2 + phi * h1 + nrm * acc2;
        const float d1 = (c1 > 0.0f) ? 1.0f : 0.0f;
        const float d2 = (c2 > 0.0f) ? 1.0f : 0.0f;

        out[OFF_H1 + idx] = fmaxf(c1, 0.0f);
        out[OFF_H2 + idx] = fmaxf(c2, 0.0f);

        const float m0 = gm0[idx], m1 = gm1[idx], m2 = gm2[idx], m3 = gm3[idx];

        const float dgr = -er * g;           // d_g_w_r
        const float dpr = -er * phi;         // d_phi_w_r
        const float dgt = -th * phi;         // d_g_w_th
        const float dpt =  th * g;           // d_phi_w_th
        const float dnr =  er * r * r / nrm; // d_norm_w_r

        out[OFF_NGM0 + idx] = d1 * (dgr * h1 + g * m0 - dpr * h2 - phi * m1 + dnr * acc1);
        out[OFF_NGM1 + idx] = d2 * (dgr * h2 + g * m1 + dpr * h1 + phi * m0 + dnr * acc2);
        out[OFF_NGM2 + idx] = d1 * (dgt * h1 + g * m2 - dpt * h2 - phi * m3);
        out[OFF_NGM3 + idx] = d2 * (dgt * h2 + g * m3 + dpt * h1 + phi * m2);

        ws[0 * BH + idx] = d1 * g;
        ws[1 * BH + idx] = d1 * phi;
        ws[2 * BH + idx] = d1 * nrm;
        ws[3 * BH + idx] = d2 * g;
        ws[4 * BH + idx] = d2 * phi;
        ws[5 * BH + idx] = d2 * nrm;
    }
}

// ---------------------------------------------------------------------------
// Kernel 2 v3: one thread per quad (max TLP/MLP, direction confirmed r14:
// dropped below top-5 cutoff) + nontemporal stores via ext_vector_type
// (outputs never re-read -> keep them out of L3 so gm4..7 stays resident;
// r13 FETCH=69MB showed L3 already absorbs half the input reads).
//   i: b = i>>14, j = (i>>6)&255, h4 = i&63. 8192 blocks x 256.
// ---------------------------------------------------------------------------
__global__ __launch_bounds__(256) void k_big(
    const float4* __restrict__ gm4, const float4* __restrict__ gm5,
    const float4* __restrict__ gm6, const float4* __restrict__ gm7,
    const float*  __restrict__ x,
    const float4* __restrict__ wsq,
    floatx4* __restrict__ o4, floatx4* __restrict__ o5,
    floatx4* __restrict__ o6, floatx4* __restrict__ o7)
{
    const int i  = blockIdx.x * 256 + threadIdx.x;   // quad index, 0..2097151
    const int b  = i >> 14;
    const int j  = (i >> 6) & (D_IN - 1);
    const int h4 = i & 63;

    const int CQ = BH / 4;                           // 8192 quads per coeff array
    const int ci = (b << 6) + h4;

    const float4 A1 = wsq[0 * CQ + ci];
    const float4 B1 = wsq[1 * CQ + ci];
    const float4 N1 = wsq[2 * CQ + ci];
    const float4 A2 = wsq[3 * CQ + ci];
    const float4 B2 = wsq[4 * CQ + ci];
    const float4 N2 = wsq[5 * CQ + ci];

    const float xv = x[(b << 8) + j];

    const float4 g4 = gm4[i], g5 = gm5[i], g6 = gm6[i], g7 = gm7[i];

    floatx4 r4, r5, r6, r7;
#define COMP(c, n)                                                    \
    r4[n] = fmaf(N1.c, xv, fmaf(A1.c, g4.c, -(B1.c * g5.c)));         \
    r5[n] = fmaf(A2.c, g5.c, B2.c * g4.c);                            \
    r6[n] = fmaf(A1.c, g6.c, -(B1.c * g7.c));                         \
    r7[n] = fmaf(N2.c, xv, fmaf(A2.c, g7.c, B2.c * g6.c));
    COMP(x, 0) COMP(y, 1) COMP(z, 2) COMP(w, 3)
#undef COMP

    __builtin_nontemporal_store(r4, &o4[i]);
    __builtin_nontemporal_store(r5, &o5[i]);
    __builtin_nontemporal_store(r6, &o6[i]);
    __builtin_nontemporal_store(r7, &o7[i]);
}

extern "C" void kernel_launch(void* const* d_in, const int* in_sizes, int n_in,
                              void* d_out, int out_size, void* d_ws, size_t ws_size,
                              hipStream_t stream) {
    const float* x_t  = (const float*)d_in[0];
    const float* hc1  = (const float*)d_in[1];
    const float* hc2  = (const float*)d_in[2];
    const float* gm0  = (const float*)d_in[3];
    const float* gm1  = (const float*)d_in[4];
    const float* gm2  = (const float*)d_in[5];
    const float* gm3  = (const float*)d_in[6];
    const float* gm4  = (const float*)d_in[7];
    const float* gm5  = (const float*)d_in[8];
    const float* gm6  = (const float*)d_in[9];
    const float* gm7  = (const float*)d_in[10];
    const float* rp   = (const float*)d_in[11];
    const float* thp  = (const float*)d_in[12];
    const float* wx1  = (const float*)d_in[13];
    const float* wx2  = (const float*)d_in[14];

    float* out = (float*)d_out;
    float* ws  = (float*)d_ws;

    k_small<<<B * 4, 256, 0, stream>>>(x_t, hc1, hc2, gm0, gm1, gm2, gm3,
                                       rp, thp, wx1, wx2, out, ws);

    const int quads = BIG / 4;                 // 2,097,152
    k_big<<<quads / 256, 256, 0, stream>>>(
        (const float4*)gm4, (const float4*)gm5, (const float4*)gm6, (const float4*)gm7,
        x_t, (const float4*)ws,
        (floatx4*)(out + OFF_NGM4), (floatx4*)(out + OFF_NGM5),
        (floatx4*)(out + OFF_NGM6), (floatx4*)(out + OFF_NGM7));
}

// Round 17
// 257.069 us; speedup vs baseline: 1.2102x; 1.0566x over previous
//
#include <hip/hip_runtime.h>

#define B    128
#define D_IN 256
#define H    256

#define BH      (B * H)            // 32768
#define BIG     (B * D_IN * H)     // 8388608
#define OFF_H1   0
#define OFF_H2   (1 * BH)
#define OFF_NGM0 (2 * BH)
#define OFF_NGM1 (3 * BH)
#define OFF_NGM2 (4 * BH)
#define OFF_NGM3 (5 * BH)
#define OFF_NGM4 (6 * BH)
#define OFF_NGM5 (OFF_NGM4 + 1 * BIG)
#define OFF_NGM6 (OFF_NGM4 + 2 * BIG)
#define OFF_NGM7 (OFF_NGM4 + 3 * BIG)

// native clang vector type — required by __builtin_nontemporal_load/store
typedef float floatx4 __attribute__((ext_vector_type(4)));

// ---------------------------------------------------------------------------
// Kernel 1 v3 (unchanged, correctness-proven): GEMV + epilogue.
// ---------------------------------------------------------------------------
__global__ __launch_bounds__(256, 2) void k_small(
    const float* __restrict__ x,   const float* __restrict__ hc1, const float* __restrict__ hc2,
    const float* __restrict__ gm0, const float* __restrict__ gm1,
    const float* __restrict__ gm2, const float* __restrict__ gm3,
    const float* __restrict__ rp,  const float* __restrict__ thp,
    const float* __restrict__ wx1, const float* __restrict__ wx2,
    float* __restrict__ out, float* __restrict__ ws)
{
    const int bid  = blockIdx.x;
    const int b    = bid >> 2;
    const int hseg = bid & 3;        // h in [hseg*64, hseg*64+64)
    const int t    = threadIdx.x;

    __shared__ float  xs[D_IN];
    __shared__ float4 s1q[16 * 16];  // [ks][hq] partials for w1x
    __shared__ float4 s2q[16 * 16];

    xs[t] = x[b * D_IN + t];
    __syncthreads();

    const int hq = t & 15;
    const int ks = t >> 4;
    const int gq = hseg * 16 + hq;

    const float4* __restrict__ wx1q = (const float4*)wx1;  // [k][64] quads
    const float4* __restrict__ wx2q = (const float4*)wx2;

    float4 a1 = make_float4(0.f, 0.f, 0.f, 0.f);
    float4 a2 = make_float4(0.f, 0.f, 0.f, 0.f);
    const int k0 = ks * 16;
#pragma unroll
    for (int kk = 0; kk < 16; ++kk) {
        const int k = k0 + kk;
        const float xv = xs[k];
        const float4 w1 = wx1q[k * 64 + gq];
        const float4 w2 = wx2q[k * 64 + gq];
        a1.x = fmaf(xv, w1.x, a1.x); a1.y = fmaf(xv, w1.y, a1.y);
        a1.z = fmaf(xv, w1.z, a1.z); a1.w = fmaf(xv, w1.w, a1.w);
        a2.x = fmaf(xv, w2.x, a2.x); a2.y = fmaf(xv, w2.y, a2.y);
        a2.z = fmaf(xv, w2.z, a2.z); a2.w = fmaf(xv, w2.w, a2.w);
    }
    s1q[ks * 16 + hq] = a1;
    s2q[ks * 16 + hq] = a2;
    __syncthreads();

    if (t < 64) {
        const int h   = hseg * 64 + t;
        const float* s1f = (const float*)s1q;
        const float* s2f = (const float*)s2q;
        float acc1 = 0.f, acc2 = 0.f;
#pragma unroll
        for (int s = 0; s < 16; ++s) {
            acc1 += s1f[s * 64 + t];
            acc2 += s2f[s * 64 + t];
        }

        const float er  = expf(rp[h]);
        const float r   = expf(-er);
        const float th  = expf(thp[h]);
        const float g   = r * cosf(th);
        const float phi = r * sinf(th);
        const float nrm = sqrtf(1.0f - r * r);

        const int idx = b * H + h;
        const float h1 = hc1[idx], h2 = hc2[idx];

        const float c1 = g * h1 - phi * h2 + nrm * acc1;
        const float c2 = g * h2 + phi * h1 + nrm * acc2;
        const float d1 = (c1 > 0.0f) ? 1.0f : 0.0f;
        const float d2 = (c2 > 0.0f) ? 1.0f : 0.0f;

        out[OFF_H1 + idx] = fmaxf(c1, 0.0f);
        out[OFF_H2 + idx] = fmaxf(c2, 0.0f);

        const float m0 = gm0[idx], m1 = gm1[idx], m2 = gm2[idx], m3 = gm3[idx];

        const float dgr = -er * g;
        const float dpr = -er * phi;
        const float dgt = -th * phi;
        const float dpt =  th * g;
        const float dnr =  er * r * r / nrm;

        out[OFF_NGM0 + idx] = d1 * (dgr * h1 + g * m0 - dpr * h2 - phi * m1 + dnr * acc1);
        out[OFF_NGM1 + idx] = d2 * (dgr * h2 + g * m1 + dpr * h1 + phi * m0 + dnr * acc2);
        out[OFF_NGM2 + idx] = d1 * (dgt * h1 + g * m2 - dpt * h2 - phi * m3);
        out[OFF_NGM3 + idx] = d2 * (dgt * h2 + g * m3 + dpt * h1 + phi * m2);

        ws[0 * BH + idx] = d1 * g;
        ws[1 * BH + idx] = d1 * phi;
        ws[2 * BH + idx] = d1 * nrm;
        ws[3 * BH + idx] = d2 * g;
        ws[4 * BH + idx] = d2 * phi;
        ws[5 * BH + idx] = d2 * nrm;
    }
}

// ---------------------------------------------------------------------------
// Kernel 2 v4: stream-pair split + 2 quads/thread + NT loads.
//   r13/r16 invariance (2.5 TB/s at occ 39% AND 70%) -> read-path cap per CU
//   (L1 miss-tracking / stream-count), not wave parallelism. Fix:
//   - group g=blockIdx>>12: g=0 does (gm4,gm5)->(o4,o5); g=1 (gm6,gm7)->(o6,o7)
//     => 2 read + 2 write streams per block (was 4+4).
//   - thread handles quads q and q+256 => block covers 512 consecutive quads
//     = 8 KB contiguous per stream; same b/h4 for both => coeffs loaded once.
//   - NT loads on gm streams (bypass L1 allocation), NT stores on outputs.
//   - launch_bounds(256,4): 64-VGPR budget, all loads in flight.
//   Algebra per quad (a = gm4|gm6, bb = gm5|gm7):
//     out_a = A1*a - B1*bb + (g?0:N1*x)   // = ngm4 | ngm6
//     out_b = A2*bb + B2*a + (g?N2*x:0)   // = ngm5 | ngm7
// ---------------------------------------------------------------------------
__global__ __launch_bounds__(256, 4) void k_big(
    const floatx4* __restrict__ gm4, const floatx4* __restrict__ gm5,
    const floatx4* __restrict__ gm6, const floatx4* __restrict__ gm7,
    const float*  __restrict__ x,
    const floatx4* __restrict__ wsq,
    floatx4* __restrict__ o4, floatx4* __restrict__ o5,
    floatx4* __restrict__ o6, floatx4* __restrict__ o7)
{
    const int g    = blockIdx.x >> 12;            // 0 or 1
    const int bid2 = blockIdx.x & 4095;
    const int q_lo = bid2 * 512 + threadIdx.x;    // first quad
    const int q_hi = q_lo + 256;                  // second quad (same b, h4; j+4)

    const int b   = q_lo >> 14;
    const int j   = (q_lo >> 6) & (D_IN - 1);
    const int h4  = q_lo & 63;
    const int CQ  = BH / 4;
    const int ci  = (b << 6) + h4;

    const floatx4* __restrict__ pa = g ? gm6 : gm4;
    const floatx4* __restrict__ pb = g ? gm7 : gm5;
    floatx4* __restrict__ oa = g ? o6 : o4;
    floatx4* __restrict__ ob = g ? o7 : o5;

    const floatx4 A1 = wsq[0 * CQ + ci];
    const floatx4 B1 = wsq[1 * CQ + ci];
    const floatx4 A2 = wsq[3 * CQ + ci];
    const floatx4 B2 = wsq[4 * CQ + ci];
    const floatx4 NN = wsq[(g ? 5 : 2) * CQ + ci];   // N2 for group B, N1 for A

    const float x_lo = x[(b << 8) + j];
    const float x_hi = x[(b << 8) + j + 4];
    const float fxa_lo = g ? 0.f : x_lo;   // x feeds out_a only in group A
    const float fxa_hi = g ? 0.f : x_hi;
    const float fxb_lo = g ? x_lo : 0.f;   // x feeds out_b only in group B
    const float fxb_hi = g ? x_hi : 0.f;

    const floatx4 a_lo = __builtin_nontemporal_load(&pa[q_lo]);
    const floatx4 b_lo = __builtin_nontemporal_load(&pb[q_lo]);
    const floatx4 a_hi = __builtin_nontemporal_load(&pa[q_hi]);
    const floatx4 b_hi = __builtin_nontemporal_load(&pb[q_hi]);

    floatx4 ra_lo, rb_lo, ra_hi, rb_hi;
#pragma unroll
    for (int n = 0; n < 4; ++n) {
        ra_lo[n] = fmaf(NN[n], fxa_lo, fmaf(A1[n], a_lo[n], -(B1[n] * b_lo[n])));
        rb_lo[n] = fmaf(NN[n], fxb_lo, fmaf(A2[n], b_lo[n],   B2[n] * a_lo[n]));
        ra_hi[n] = fmaf(NN[n], fxa_hi, fmaf(A1[n], a_hi[n], -(B1[n] * b_hi[n])));
        rb_hi[n] = fmaf(NN[n], fxb_hi, fmaf(A2[n], b_hi[n],   B2[n] * a_hi[n]));
    }

    __builtin_nontemporal_store(ra_lo, &oa[q_lo]);
    __builtin_nontemporal_store(rb_lo, &ob[q_lo]);
    __builtin_nontemporal_store(ra_hi, &oa[q_hi]);
    __builtin_nontemporal_store(rb_hi, &ob[q_hi]);
}

extern "C" void kernel_launch(void* const* d_in, const int* in_sizes, int n_in,
                              void* d_out, int out_size, void* d_ws, size_t ws_size,
                              hipStream_t stream) {
    const float* x_t  = (const float*)d_in[0];
    const float* hc1  = (const float*)d_in[1];
    const float* hc2  = (const float*)d_in[2];
    const float* gm0  = (const float*)d_in[3];
    const float* gm1  = (const float*)d_in[4];
    const float* gm2  = (const float*)d_in[5];
    const float* gm3  = (const float*)d_in[6];
    const float* gm4  = (const float*)d_in[7];
    const float* gm5  = (const float*)d_in[8];
    const float* gm6  = (const float*)d_in[9];
    const float* gm7  = (const float*)d_in[10];
    const float* rp   = (const float*)d_in[11];
    const float* thp  = (const float*)d_in[12];
    const float* wx1  = (const float*)d_in[13];
    const float* wx2  = (const float*)d_in[14];

    float* out = (float*)d_out;
    float* ws  = (float*)d_ws;

    k_small<<<B * 4, 256, 0, stream>>>(x_t, hc1, hc2, gm0, gm1, gm2, gm3,
                                       rp, thp, wx1, wx2, out, ws);

    // 2 groups x 4096 blocks; each block: 512 quads x (2 streams in, 2 out)
    k_big<<<8192, 256, 0, stream>>>(
        (const floatx4*)gm4, (const floatx4*)gm5, (const floatx4*)gm6, (const floatx4*)gm7,
        x_t, (const floatx4*)ws,
        (floatx4*)(out + OFF_NGM4), (floatx4*)(out + OFF_NGM5),
        (floatx4*)(out + OFF_NGM6), (floatx4*)(out + OFF_NGM7));
}